// Round 1
// baseline (261.275 us; speedup 1.0000x reference)
//
#include <hip/hip_runtime.h>
#include <hip/hip_bf16.h>

#define CC 8
#define TT 4096
#define EE 1024
#define HH 16
#define DD 64
#define TOKB 32              // tokens per k1 block
#define TBLK (TT / TOKB)     // 128 t-blocks per chunk c
#define OT 8                 // tokens per k3 block

typedef __attribute__((ext_vector_type(8))) short short8;
typedef __attribute__((ext_vector_type(4))) float f32x4;

static __device__ __forceinline__ short f2bf(float f) {
    unsigned u = __builtin_bit_cast(unsigned, f);
    u += 0x7fff + ((u >> 16) & 1);   // RNE to bf16 (inputs are finite normals)
    return (short)(u >> 16);
}

static __device__ __forceinline__ f32x4 mfma16(short8 a, short8 b, f32x4 c) {
    return __builtin_amdgcn_mfma_f32_16x16x32_bf16(a, b, c, 0, 0, 0);
}

// k1: per token (c,t): s[c,t,h] = (x_h Wq^T)·(x_h Wk^T)/32 for all 16 heads via MFMA,
//     plus per-block partial sums of x (slot = h*64+d) for the vsum reduction.
__global__ __launch_bounds__(256, 2)
void k1_scores(const float* __restrict__ x, const float* __restrict__ Wq,
               const float* __restrict__ Wk, float* __restrict__ s_out,
               float* __restrict__ part_out) {
    const int bid = blockIdx.x;          // c*TBLK + tb
    const int c = bid >> 7, tb = bid & (TBLK - 1);
    const int tid = threadIdx.x;
    const int w = tid >> 6;              // wave 0..3
    const int lane = tid & 63;
    const int lg = lane >> 4;            // lane group 0..3 (k-chunk / row-group)
    const int lr = lane & 15;            // 0..15

    __shared__ short fragW[16][512];     // B-frags: f = which*8 + et*2 + kc, [f][lane*8+j]
    __shared__ float red[4][1024];       // per-wave xsum partials in slot space

    // --- stage Wq/Wk B-fragments (bf16) into LDS ---
    for (int rep = 0; rep < 4; ++rep) {
        int slot = rep * 256 + tid;      // f*64 + ln
        int f = slot >> 6, ln = slot & 63;
        int which = f >> 3, et = (f >> 1) & 3, kc = f & 1;
        const float* Wp = which ? Wk : Wq;
        // B[k][col] = W[col][k]: lane ln holds W[et*16+(ln&15)][kc*32+(ln>>4)*8 + j]
        const float* src = Wp + (et * 16 + (ln & 15)) * 64 + kc * 32 + (ln >> 4) * 8;
        short8 v;
        #pragma unroll
        for (int j = 0; j < 8; ++j) v[j] = f2bf(src[j]);
        *reinterpret_cast<short8*>(&fragW[f][ln * 8]) = v;
    }
    __syncthreads();

    const float* xbase = x + (size_t)(c * TT + tb * TOKB) * EE;
    f32x4 xa0 = {0,0,0,0}, xa1 = {0,0,0,0}, xa2 = {0,0,0,0}, xa3 = {0,0,0,0};

    for (int it = 0; it < TOKB / 4; ++it) {
        const int tloc = it * 4 + w;
        const float* tp = xbase + (size_t)tloc * EE + lr * 64 + lg * 8;
        // A-frag source: lane holds x[h=lr][d = kc*32 + lg*8 + j]
        f32x4 f0 = *(const f32x4*)(tp);
        f32x4 f1 = *(const f32x4*)(tp + 4);
        f32x4 f2 = *(const f32x4*)(tp + 32);
        f32x4 f3 = *(const f32x4*)(tp + 36);
        xa0 += f0; xa1 += f1; xa2 += f2; xa3 += f3;

        short8 a0, a1;
        #pragma unroll
        for (int j = 0; j < 4; ++j) { a0[j] = f2bf(f0[j]); a0[j+4] = f2bf(f1[j]); }
        #pragma unroll
        for (int j = 0; j < 4; ++j) { a1[j] = f2bf(f2[j]); a1[j+4] = f2bf(f3[j]); }

        float p0 = 0.f, p1 = 0.f, p2 = 0.f, p3 = 0.f;
        #pragma unroll
        for (int et = 0; et < 4; ++et) {
            short8 bq0 = *(const short8*)&fragW[et * 2 + 0][lane * 8];
            short8 bq1 = *(const short8*)&fragW[et * 2 + 1][lane * 8];
            f32x4 qa = {0,0,0,0};
            qa = mfma16(a0, bq0, qa);
            qa = mfma16(a1, bq1, qa);
            short8 bk0 = *(const short8*)&fragW[8 + et * 2 + 0][lane * 8];
            short8 bk1 = *(const short8*)&fragW[8 + et * 2 + 1][lane * 8];
            f32x4 ka = {0,0,0,0};
            ka = mfma16(a0, bk0, ka);
            ka = mfma16(a1, bk1, ka);
            // lane holds q/k[h = lg*4+i][e = et*16+lr]
            p0 += qa[0] * ka[0]; p1 += qa[1] * ka[1];
            p2 += qa[2] * ka[2]; p3 += qa[3] * ka[3];
        }
        // reduce over e (the 16 lanes lr=0..15 within group lg)
        #pragma unroll
        for (int m = 1; m < 16; m <<= 1) {
            p0 += __shfl_xor(p0, m);
            p1 += __shfl_xor(p1, m);
            p2 += __shfl_xor(p2, m);
            p3 += __shfl_xor(p3, m);
        }
        if (lr == 0) {
            const float inv = 1.0f / 32.0f;   // 1/sqrt(E)
            int t = tb * TOKB + tloc;
            f32x4 sv = { p0 * inv, p1 * inv, p2 * inv, p3 * inv };
            *(f32x4*)&s_out[((size_t)c * TT + t) * HH + lg * 4] = sv;
        }
    }

    // --- xsum partials: lane slot base = lr*64 + lg*8 (h=lr, d=lg*8..) ---
    {
        int base = lr * 64 + lg * 8;
        *(f32x4*)&red[w][base + 0]  = xa0;
        *(f32x4*)&red[w][base + 4]  = xa1;
        *(f32x4*)&red[w][base + 32] = xa2;
        *(f32x4*)&red[w][base + 36] = xa3;
    }
    __syncthreads();
    float* pb = part_out + (size_t)bid * 1024;
    #pragma unroll
    for (int k = 0; k < 4; ++k) {
        int slot = k * 256 + tid;
        pb[slot] = red[0][slot] + red[1][slot] + red[2][slot] + red[3][slot];
    }
}

// k2: block = (c,h). xsum[c,h,:] = sum of 128 partials; vsum[c,h,e] = sum_d Wv[e,d]*xsum[d]
__global__ __launch_bounds__(256)
void k2_vsum(const float* __restrict__ part, const float* __restrict__ Wv,
             float* __restrict__ vsum) {
    const int b = blockIdx.x;            // c*16 + h
    const int c = b >> 4, h = b & 15;
    const int tid = threadIdx.x;
    __shared__ float xs[4][64];
    __shared__ float xsum[64];

    const int d = tid & 63, g = tid >> 6;
    float a = 0.f;
    for (int tb = g * 32; tb < g * 32 + 32; ++tb)
        a += part[(size_t)(c * TBLK + tb) * 1024 + h * 64 + d];
    xs[g][d] = a;
    __syncthreads();
    if (tid < 64) xsum[tid] = xs[0][tid] + xs[1][tid] + xs[2][tid] + xs[3][tid];
    __syncthreads();
    if (tid < 64) {
        const float* wr = Wv + tid * 64;     // row e = tid
        float acc = 0.f;
        #pragma unroll 16
        for (int dd = 0; dd < 64; ++dd) acc += wr[dd] * xsum[dd];
        vsum[(size_t)c * 1024 + h * 64 + tid] = acc;
    }
}

// k3: softmax over c (8 values) + out[c,t,e] = prob[c,t,e>>6] * vsum[c,e]
__global__ __launch_bounds__(256)
void k3_out(const float* __restrict__ s_in, const float* __restrict__ vsum,
            float* __restrict__ out) {
    const int b = blockIdx.x;            // t0 = b*OT
    const int tid = threadIdx.x;
    __shared__ float lv[CC * 1024];      // vsum
    __shared__ float ls[CC][OT * HH];    // scores -> probs

    #pragma unroll
    for (int r = 0; r < 8; ++r) {
        int idx = r * 1024 + tid * 4;
        *(f32x4*)&lv[idx] = *(const f32x4*)&vsum[idx];
    }
    const int t0 = b * OT;
    if (tid < OT * HH) {
        #pragma unroll
        for (int c = 0; c < CC; ++c)
            ls[c][tid] = s_in[((size_t)c * TT + t0) * HH + tid];
    }
    __syncthreads();
    if (tid < OT * HH) {
        float v[CC], m = -1e30f;
        #pragma unroll
        for (int c = 0; c < CC; ++c) { v[c] = ls[c][tid]; m = fmaxf(m, v[c]); }
        float sum = 0.f;
        #pragma unroll
        for (int c = 0; c < CC; ++c) { v[c] = expf(v[c] - m); sum += v[c]; }
        float r = 1.0f / sum;
        #pragma unroll
        for (int c = 0; c < CC; ++c) ls[c][tid] = v[c] * r;
    }
    __syncthreads();
    const int h = tid >> 4;              // (tid*4)>>6
    #pragma unroll
    for (int c = 0; c < CC; ++c) {
        f32x4 vv = *(f32x4*)&lv[c * 1024 + tid * 4];
        #pragma unroll
        for (int t = 0; t < OT; ++t) {
            float p = ls[c][t * HH + h];
            f32x4 o = { vv[0] * p, vv[1] * p, vv[2] * p, vv[3] * p };
            *(f32x4*)&out[((size_t)c * TT + t0 + t) * EE + tid * 4] = o;
        }
    }
}

extern "C" void kernel_launch(void* const* d_in, const int* in_sizes, int n_in,
                              void* d_out, int out_size, void* d_ws, size_t ws_size,
                              hipStream_t stream) {
    const float* x  = (const float*)d_in[0];
    const float* Wq = (const float*)d_in[1];
    const float* Wk = (const float*)d_in[2];
    const float* Wv = (const float*)d_in[3];
    float* out = (float*)d_out;
    float* ws  = (float*)d_ws;

    float* s    = ws;                         // C*T*H      = 524288 f32 (2 MiB)
    float* part = ws + 524288;                // 1024*1024  f32 (4 MiB)
    float* vsum = ws + 524288 + 1024 * 1024;  // 8192 f32 (32 KiB)

    k1_scores<<<CC * TBLK, 256, 0, stream>>>(x, Wq, Wk, s, part);
    k2_vsum  <<<CC * HH,   256, 0, stream>>>(part, Wv, vsum);
    k3_out   <<<TT / OT,   256, 0, stream>>>(s, vsum, out);
}